// Round 9
// baseline (37.440 us; speedup 1.0000x reference)
//
#include <hip/hip_runtime.h>
#include <cstdint>

namespace {

constexpr int NB = 320;   // batch
constexpr int ND = 128;   // feature dim
constexpr int NC = 80;    // label dim
constexpr int NANCH = 30;
constexpr int NW = 5;     // 64-bit words per 320-bit row
constexpr int LSTR = 129; // padded LDS row stride (floats): bank=(lane+d)%32, conflict-free

// ---- workspace layout (byte offsets) ----
constexpr size_t OFF_DIV  = 0;       // float[320]
constexpr size_t OFF_ASUM = 1280;    // double[320] (8-aligned)
constexpr size_t OFF_ACNT = 3840;    // int[320]
constexpr size_t OFF_PACK = 5120;    // u64[640]

// K0: pack all 320 label rows once (per-thread register packing).
__global__ __launch_bounds__(64) void k_pack(const int* __restrict__ label,
                                             unsigned long long* __restrict__ packed) {
    const int r = blockIdx.x * 64 + threadIdx.x;          // 0..319
    const int4* lp = reinterpret_cast<const int4*>(label + r * NC);  // 320B-aligned
    unsigned long long j0 = 0, j1 = 0;
#pragma unroll
    for (int q = 0; q < 16; ++q) {                        // c = 0..63
        int4 v = lp[q];
        j0 |= (unsigned long long)(v.x != 0) << (4 * q + 0);
        j0 |= (unsigned long long)(v.y != 0) << (4 * q + 1);
        j0 |= (unsigned long long)(v.z != 0) << (4 * q + 2);
        j0 |= (unsigned long long)(v.w != 0) << (4 * q + 3);
    }
#pragma unroll
    for (int q = 16; q < 20; ++q) {                       // c = 64..79
        int4 v = lp[q];
        const int b = 4 * (q - 16);
        j1 |= (unsigned long long)(v.x != 0) << (b + 0);
        j1 |= (unsigned long long)(v.y != 0) << (b + 1);
        j1 |= (unsigned long long)(v.z != 0) << (b + 2);
        j1 |= (unsigned long long)(v.w != 0) << (b + 3);
    }
    packed[2 * r]     = j0;
    packed[2 * r + 1] = j1;
}

// K1: block a does everything for row a. tgt is staged through LDS in 64-row
// chunks with coalesced loads; dots read LDS at stride 129 (conflict-free).
// All FP accumulation orders are identical to the absmax-0.0 lineage.
__global__ __launch_bounds__(256) void k_main(
    const float* __restrict__ src,
    const float* __restrict__ tgt,
    const unsigned long long* __restrict__ packed,
    float* __restrict__ divr,
    double* __restrict__ asum,
    int* __restrict__ acnt)
{
    const int a = blockIdx.x;
    const int tid = threadIdx.x;
    const int w = tid >> 6, lane = tid & 63;

    __shared__ float sa[ND];
    __shared__ float snsa;
    __shared__ float red[256];
    __shared__ unsigned long long pk[2 * NB];   // 5 KB
    __shared__ float tch[64 * LSTR];            // 33 KB chunk of tgt
    __shared__ float fdrow[NB];
    __shared__ unsigned long long pmask[NW], nmask[NW];
    __shared__ double wsum[4];

    if (tid < ND) sa[tid] = src[a * ND + tid];
    if (w == 0) {
        float s0 = src[a * ND + lane];
        float s1 = src[a * ND + lane + 64];
        float v = s0 * s0 + s1 * s1;
        for (int off = 32; off > 0; off >>= 1) v += __shfl_down(v, off);
        if (lane == 0) snsa = sqrtf(v);
    }
    for (int q = tid; q < 2 * NB; q += 256) pk[q] = packed[q];  // coalesced
    __syncthreads();

    const unsigned long long a0 = pk[2 * a], a1 = pk[2 * a + 1];
    const float nsa = snsa;

    // ---- fd phase: 5 chunks of 64 tgt rows ----
    float acc = 0.f;
    for (int c = 0; c < 5; ++c) {
        // stage chunk: coalesced float4 global loads -> padded LDS
        for (int q = 0; q < 8; ++q) {
            const int u = tid + 256 * q;                  // float4 idx in chunk
            float4 v = reinterpret_cast<const float4*>(tgt)[c * 2048 + u];
            const int r = u >> 5, d4 = (u & 31) << 2;
            float* dst = &tch[r * LSTR + d4];
            dst[0] = v.x; dst[1] = v.y; dst[2] = v.z; dst[3] = v.w;
        }
        __syncthreads();
        // compute: thread's own row j if it falls in this chunk (wave-uniform)
        const int j = (c < 4) ? (((tid >> 6) == c) ? tid : -1)
                              : ((tid < 64) ? tid + 256 : -1);
        if (j >= 0) {
            const float* lrow = &tch[(j - (c << 6)) * LSTR];
            float dot = 0.f, tn = 0.f;
#pragma unroll
            for (int d = 0; d < ND / 4; ++d) {
                float x = lrow[4 * d + 0], y = lrow[4 * d + 1];
                float z = lrow[4 * d + 2], t3 = lrow[4 * d + 3];
                dot += sa[4 * d + 0] * x + sa[4 * d + 1] * y +
                       sa[4 * d + 2] * z + sa[4 * d + 3] * t3;
                tn += x * x + y * y + z * z + t3 * t3;
            }
            float sim = dot / fmaxf(nsa * sqrtf(tn), 1e-8f);
            float f = fmaxf(1.0f - sim, 0.0f);
            fdrow[j] = f;
            acc += f;                    // tid<64: chunk0 then chunk4 -> order kept
        }
        __syncthreads();                 // chunk consumed before next stage
    }

    // ---- diversity: identical red-tree ----
    red[tid] = acc;
    __syncthreads();
    for (int st = 128; st > 0; st >>= 1) {
        if (tid < st) red[tid] += red[tid + st];
        __syncthreads();
    }
    if (tid == 0) divr[a] = red[0] / (float)NB;

    // ---- classification from LDS-packed labels (bit-identical masks) ----
    const float sna = sqrtf((float)(__popcll(a0) + __popcll(a1)));
#pragma unroll
    for (int it = 0; it < 2; ++it) {
        const int jj = tid + 256 * it;               // wave-uniform guard
        if (jj < NB) {
            const unsigned long long j0 = pk[2 * jj], j1 = pk[2 * jj + 1];
            const float snj = sqrtf((float)(__popcll(j0) + __popcll(j1)));
            const float denom = sna * snj;
            const float dotf = (float)(__popcll(a0 & j0) + __popcll(a1 & j1));
            const float ld = 1.0f - fminf(1.0f, dotf / denom);
            const bool valid = (jj != a) && (denom > 0.f); // 0-label -> NaN in ref -> excluded
            unsigned long long pb = __ballot(valid && (ld <= 0.2f));
            unsigned long long nb = __ballot(valid && (ld >= 0.5f));
            if (lane == 0) { pmask[jj >> 6] = pb; nmask[jj >> 6] = nb; }
        }
    }
    __syncthreads();

    // ---- speculative triplet sum for row a (pos/neg disjoint -> p != n) ----
    double s = 0.0;
#pragma unroll
    for (int it = 0; it < 2; ++it) {
        const int jj = tid + 256 * it;
        if (jj < NB && ((nmask[jj >> 6] >> (jj & 63)) & 1ull)) {
            const float fn = fdrow[jj];
#pragma unroll
            for (int wd = 0; wd < NW; ++wd) {
                unsigned long long m = pmask[wd];
                while (m) {
                    const int b = __builtin_ctzll(m);
                    m &= m - 1;
                    float v = fdrow[wd * 64 + b] - fn + 0.5f;
                    if (v > 0.f) s += (double)v;
                }
            }
        }
    }
    for (int off = 32; off > 0; off >>= 1) s += __shfl_down(s, off);
    if (lane == 0) wsum[w] = s;
    __syncthreads();
    if (tid == 0) {
        int P = 0, N = 0;
#pragma unroll
        for (int wd = 0; wd < NW; ++wd) {
            P += __popcll(pmask[wd]);
            N += __popcll(nmask[wd]);
        }
        asum[a] = wsum[0] + wsum[1] + wsum[2] + wsum[3];
        acnt[a] = P * N;
    }
}

// K2: tiny tail -- rank-based top-30, gather precomputed (sum, count), divide.
__global__ __launch_bounds__(320) void k_final(
    const float* __restrict__ divr,
    const double* __restrict__ asum,
    const int* __restrict__ acnt,
    float* __restrict__ out)
{
    const int tid = threadIdx.x;
    __shared__ float dv[NB];
    __shared__ int alist[NANCH];
    __shared__ double sl[NANCH];
    __shared__ int cl[NANCH];

    dv[tid] = divr[tid];
    __syncthreads();

    const float ve = dv[tid];
    int rank = 0;
#pragma unroll 8
    for (int j = 0; j < NB; ++j) {
        float vj = dv[j];
        rank += (vj > ve) || (vj == ve && j < tid);
    }
    if (rank < NANCH) alist[rank] = tid;   // ranks unique; = lax.top_k order
    __syncthreads();

    if (tid < NANCH) {
        sl[tid] = asum[alist[tid]];
        cl[tid] = acnt[alist[tid]];
    }
    __syncthreads();
    if (tid == 0) {
        double S = 0.0;
        long long C = 0;
        for (int r = 0; r < NANCH; ++r) { S += sl[r]; C += cl[r]; }
        out[0] = (float)(S / ((double)C + 1e-4));
    }
}

} // namespace

extern "C" void kernel_launch(void* const* d_in, const int* in_sizes, int n_in,
                              void* d_out, int out_size, void* d_ws, size_t ws_size,
                              hipStream_t stream) {
    const int* label = (const int*)d_in[0];
    const float* src = (const float*)d_in[1];
    const float* tgt = (const float*)d_in[2];

    char* ws = (char*)d_ws;
    float* divr  = (float*)(ws + OFF_DIV);
    double* asum = (double*)(ws + OFF_ASUM);
    int* acnt    = (int*)(ws + OFF_ACNT);
    unsigned long long* packed = (unsigned long long*)(ws + OFF_PACK);

    k_pack <<<5, 64, 0, stream>>>(label, packed);
    k_main <<<NB, 256, 0, stream>>>(src, tgt, packed, divr, asum, acnt);
    k_final<<<1, 320, 0, stream>>>(divr, asum, acnt, (float*)d_out);
}

// Round 10
// 31.337 us; speedup vs baseline: 1.1947x; 1.1947x over previous
//
#include <hip/hip_runtime.h>
#include <cstdint>

namespace {

constexpr int NB = 320;   // batch
constexpr int ND = 128;   // feature dim
constexpr int NC = 80;    // label dim
constexpr int NANCH = 30;
constexpr int NW = 5;     // 64-bit words per 320-bit row

// ---- workspace layout (byte offsets) ----
constexpr size_t OFF_DIV  = 0;        // float[320]
constexpr size_t OFF_ASUM = 1280;     // double[320]
constexpr size_t OFF_ACNT = 3840;     // int[320]
constexpr size_t OFF_PACK = 5120;     // u64[640]
constexpr size_t OFF_TGTT = 10240;    // float2[64][320] = 163840 B (tgt transposed)

// K0: transpose tgt (320x128 -> float2[64][320], both sides coalesced via LDS
// tile) + pack all 320 label rows (wave 0 of each block, 64 rows/block).
__global__ __launch_bounds__(256) void k_prep(
    const float* __restrict__ tgt,
    const int* __restrict__ label,
    float2* __restrict__ tgtT2,
    unsigned long long* __restrict__ packed)
{
    const int tid = threadIdx.x;
    const int w = tid >> 6, lane = tid & 63;
    const int r0 = blockIdx.x * 64;            // 5 blocks x 64 rows

    __shared__ float tile[64][133];            // pad 133: store 4-way-ish, load 2-way

    // ---- label packing: wave 0, one row per lane ----
    if (w == 0) {
        const int r = r0 + lane;
        const int4* lp = reinterpret_cast<const int4*>(label + r * NC);
        unsigned long long j0 = 0, j1 = 0;
#pragma unroll
        for (int q = 0; q < 16; ++q) {         // c = 0..63
            int4 v = lp[q];
            j0 |= (unsigned long long)(v.x != 0) << (4 * q + 0);
            j0 |= (unsigned long long)(v.y != 0) << (4 * q + 1);
            j0 |= (unsigned long long)(v.z != 0) << (4 * q + 2);
            j0 |= (unsigned long long)(v.w != 0) << (4 * q + 3);
        }
#pragma unroll
        for (int q = 16; q < 20; ++q) {        // c = 64..79
            int4 v = lp[q];
            const int b = 4 * (q - 16);
            j1 |= (unsigned long long)(v.x != 0) << (b + 0);
            j1 |= (unsigned long long)(v.y != 0) << (b + 1);
            j1 |= (unsigned long long)(v.z != 0) << (b + 2);
            j1 |= (unsigned long long)(v.w != 0) << (b + 3);
        }
        packed[2 * r]     = j0;
        packed[2 * r + 1] = j1;
    }

    // ---- transpose: coalesced float4 read -> LDS tile ----
#pragma unroll
    for (int it = 0; it < 8; ++it) {
        const int f4 = it * 256 + tid;         // float4 index within 64x128 slab
        float4 v = reinterpret_cast<const float4*>(tgt)[r0 * (ND / 4) + f4];
        const int r = f4 >> 5, d4 = (f4 & 31) << 2;
        tile[r][d4 + 0] = v.x; tile[r][d4 + 1] = v.y;
        tile[r][d4 + 2] = v.z; tile[r][d4 + 3] = v.w;
    }
    __syncthreads();

    // ---- coalesced float2 write: tgtT2[d2][r0+rr] ----
#pragma unroll
    for (int it = 0; it < 16; ++it) {
        const int d2 = it * 4 + w;             // 0..63
        float2 o;
        o.x = tile[lane][2 * d2 + 0];
        o.y = tile[lane][2 * d2 + 1];
        tgtT2[d2 * NB + r0 + lane] = o;
    }
}

// K1: block a does everything for row a, all loads coalesced.
// fd expression tree identical to the absmax-0.0 lineage (values exact copies).
__global__ __launch_bounds__(256) void k_main(
    const float* __restrict__ src,
    const float2* __restrict__ tgtT2,
    const unsigned long long* __restrict__ packed,
    float* __restrict__ divr,
    double* __restrict__ asum,
    int* __restrict__ acnt)
{
    const int a = blockIdx.x;
    const int tid = threadIdx.x;
    const int w = tid >> 6, lane = tid & 63;

    __shared__ float sa[ND];
    __shared__ float snsa;
    __shared__ float red[256];
    __shared__ unsigned long long pk[2 * NB];   // 5 KB
    __shared__ float fdrow[NB];
    __shared__ unsigned long long pmask[NW], nmask[NW];
    __shared__ double wsum[4];

    if (tid < ND) sa[tid] = src[a * ND + tid];
    if (w == 0) {
        float s0 = src[a * ND + lane];
        float s1 = src[a * ND + lane + 64];
        float v = s0 * s0 + s1 * s1;
        for (int off = 32; off > 0; off >>= 1) v += __shfl_down(v, off);
        if (lane == 0) snsa = sqrtf(v);
    }
    for (int q = tid; q < 2 * NB; q += 256) pk[q] = packed[q];  // coalesced
    __syncthreads();

    const unsigned long long a0 = pk[2 * a], a1 = pk[2 * a + 1];
    const float nsa = snsa;

    // ---- fd: thread t handles row t (and t+256); column reads = coalesced ----
    float acc = 0.f;
#pragma unroll
    for (int it = 0; it < 2; ++it) {
        const int j = tid + 256 * it;          // wave-uniform guard (320=5*64)
        if (j < NB) {
            float dot = 0.f, tn = 0.f;
#pragma unroll
            for (int d = 0; d < ND / 4; ++d) {
                float2 u = tgtT2[(2 * d + 0) * NB + j];   // (x, y)
                float2 v = tgtT2[(2 * d + 1) * NB + j];   // (z, w)
                dot += sa[4 * d + 0] * u.x + sa[4 * d + 1] * u.y +
                       sa[4 * d + 2] * v.x + sa[4 * d + 3] * v.y;
                tn += u.x * u.x + u.y * u.y + v.x * v.x + v.y * v.y;
            }
            float sim = dot / fmaxf(nsa * sqrtf(tn), 1e-8f);
            float f = fmaxf(1.0f - sim, 0.0f);
            fdrow[j] = f;
            acc += f;                          // j=tid then tid+256: order kept
        }
    }

    // ---- diversity: identical red-tree ----
    red[tid] = acc;
    __syncthreads();
    for (int st = 128; st > 0; st >>= 1) {
        if (tid < st) red[tid] += red[tid + st];
        __syncthreads();
    }
    if (tid == 0) divr[a] = red[0] / (float)NB;

    // ---- classification from LDS-packed labels (bit-identical masks) ----
    const float sna = sqrtf((float)(__popcll(a0) + __popcll(a1)));
#pragma unroll
    for (int it = 0; it < 2; ++it) {
        const int jj = tid + 256 * it;         // wave-uniform guard
        if (jj < NB) {
            const unsigned long long j0 = pk[2 * jj], j1 = pk[2 * jj + 1];
            const float snj = sqrtf((float)(__popcll(j0) + __popcll(j1)));
            const float denom = sna * snj;
            const float dotf = (float)(__popcll(a0 & j0) + __popcll(a1 & j1));
            const float ld = 1.0f - fminf(1.0f, dotf / denom);
            const bool valid = (jj != a) && (denom > 0.f); // 0-label -> NaN in ref -> excluded
            unsigned long long pb = __ballot(valid && (ld <= 0.2f));
            unsigned long long nb = __ballot(valid && (ld >= 0.5f));
            if (lane == 0) { pmask[jj >> 6] = pb; nmask[jj >> 6] = nb; }
        }
    }
    __syncthreads();

    // ---- speculative triplet sum for row a (pos/neg disjoint -> p != n) ----
    double s = 0.0;
#pragma unroll
    for (int it = 0; it < 2; ++it) {
        const int jj = tid + 256 * it;
        if (jj < NB && ((nmask[jj >> 6] >> (jj & 63)) & 1ull)) {
            const float fn = fdrow[jj];
#pragma unroll
            for (int wd = 0; wd < NW; ++wd) {
                unsigned long long m = pmask[wd];
                while (m) {
                    const int b = __builtin_ctzll(m);
                    m &= m - 1;
                    float v = fdrow[wd * 64 + b] - fn + 0.5f;
                    if (v > 0.f) s += (double)v;
                }
            }
        }
    }
    for (int off = 32; off > 0; off >>= 1) s += __shfl_down(s, off);
    if (lane == 0) wsum[w] = s;
    __syncthreads();
    if (tid == 0) {
        int P = 0, N = 0;
#pragma unroll
        for (int wd = 0; wd < NW; ++wd) {
            P += __popcll(pmask[wd]);
            N += __popcll(nmask[wd]);
        }
        asum[a] = wsum[0] + wsum[1] + wsum[2] + wsum[3];
        acnt[a] = P * N;
    }
}

// K2: tiny tail -- rank-based top-30, gather precomputed (sum, count), divide.
__global__ __launch_bounds__(320) void k_final(
    const float* __restrict__ divr,
    const double* __restrict__ asum,
    const int* __restrict__ acnt,
    float* __restrict__ out)
{
    const int tid = threadIdx.x;
    __shared__ float dv[NB];
    __shared__ int alist[NANCH];
    __shared__ double sl[NANCH];
    __shared__ int cl[NANCH];

    dv[tid] = divr[tid];
    __syncthreads();

    const float ve = dv[tid];
    int rank = 0;
#pragma unroll 8
    for (int j = 0; j < NB; ++j) {
        float vj = dv[j];
        rank += (vj > ve) || (vj == ve && j < tid);
    }
    if (rank < NANCH) alist[rank] = tid;   // ranks unique; = lax.top_k order
    __syncthreads();

    if (tid < NANCH) {
        sl[tid] = asum[alist[tid]];
        cl[tid] = acnt[alist[tid]];
    }
    __syncthreads();
    if (tid == 0) {
        double S = 0.0;
        long long C = 0;
        for (int r = 0; r < NANCH; ++r) { S += sl[r]; C += cl[r]; }
        out[0] = (float)(S / ((double)C + 1e-4));
    }
}

} // namespace

extern "C" void kernel_launch(void* const* d_in, const int* in_sizes, int n_in,
                              void* d_out, int out_size, void* d_ws, size_t ws_size,
                              hipStream_t stream) {
    const int* label = (const int*)d_in[0];
    const float* src = (const float*)d_in[1];
    const float* tgt = (const float*)d_in[2];

    char* ws = (char*)d_ws;
    float* divr  = (float*)(ws + OFF_DIV);
    double* asum = (double*)(ws + OFF_ASUM);
    int* acnt    = (int*)(ws + OFF_ACNT);
    unsigned long long* packed = (unsigned long long*)(ws + OFF_PACK);
    float2* tgtT2 = (float2*)(ws + OFF_TGTT);

    k_prep <<<5, 256, 0, stream>>>(tgt, label, tgtT2, packed);
    k_main <<<NB, 256, 0, stream>>>(src, tgtT2, packed, divr, asum, acnt);
    k_final<<<1, 320, 0, stream>>>(divr, asum, acnt, (float*)d_out);
}